// Round 1
// baseline (130.941 us; speedup 1.0000x reference)
//
#include <hip/hip_runtime.h>

#define BATCH 32
#define N 1024
#define NROWS (BATCH * N)
#define TOL2 1e-12f   // (1e-6)^2

// ---------------------------------------------------------------------------
// init: v = ones (lives in d_out), zero the control scalars in ws
// ---------------------------------------------------------------------------
__global__ __launch_bounds__(256) void pi_init(float* __restrict__ v,
                                               float* __restrict__ diff,
                                               int* __restrict__ ctr,
                                               int* __restrict__ done) {
  const int i = blockIdx.x * 256 + threadIdx.x;
  if (i < NROWS) v[i] = 1.0f;
  if (i == 0) { *diff = 0.0f; *ctr = 0; *done = 0; }
}

// ---------------------------------------------------------------------------
// matvec: y[b,r] = dot(M[b,r,:], v[b,:])   -- one wave (64 lanes) per row.
// Each lane: 4x float4 coalesced loads (16 elements), then shuffle reduce.
// Early-outs (uniformly) once the global convergence flag is set.
// ---------------------------------------------------------------------------
__global__ __launch_bounds__(256) void pi_matvec(const float* __restrict__ M,
                                                 const float* __restrict__ v,
                                                 float* __restrict__ y,
                                                 const int* __restrict__ done) {
  if (*done) return;
  const int wid  = (blockIdx.x * 256 + threadIdx.x) >> 6;  // global row id
  const int lane = threadIdx.x & 63;
  const int b    = wid >> 10;                               // batch
  const float4* Mrow = (const float4*)(M + (size_t)wid * N);
  const float4* vb   = (const float4*)(v + b * N);
  float acc = 0.0f;
#pragma unroll
  for (int k = 0; k < 4; ++k) {
    const int c = lane + 64 * k;          // float4 chunk index, coalesced
    const float4 m = Mrow[c];
    const float4 x = vb[c];
    acc += m.x * x.x + m.y * x.y + m.z * x.z + m.w * x.w;
  }
#pragma unroll
  for (int off = 32; off; off >>= 1) acc += __shfl_down(acc, off, 64);
  if (lane == 0) y[wid] = acc;
}

// ---------------------------------------------------------------------------
// finish: one block per batch.
//   norm[b] = ||y[b,:]||;  vn = y/norm;  diff += ||vn - v||^2;  v = vn
// Last block to arrive evaluates the global convergence check and resets
// the accumulators for the next iteration.
// ---------------------------------------------------------------------------
__global__ __launch_bounds__(256) void pi_finish(float* __restrict__ v,
                                                 const float* __restrict__ y,
                                                 float* __restrict__ diff,
                                                 int* __restrict__ ctr,
                                                 int* __restrict__ done) {
  if (*done) return;
  const int b = blockIdx.x;
  const int t = threadIdx.x;
  __shared__ float red[4];
  __shared__ float rn_s;

  const float4 q = ((const float4*)(y + (size_t)b * N))[t];
  float s = q.x * q.x + q.y * q.y + q.z * q.z + q.w * q.w;
#pragma unroll
  for (int off = 32; off; off >>= 1) s += __shfl_down(s, off, 64);
  if ((t & 63) == 0) red[t >> 6] = s;
  __syncthreads();
  if (t == 0) {
    const float nrm = sqrtf(red[0] + red[1] + red[2] + red[3]);
    rn_s = 1.0f / nrm;
  }
  __syncthreads();
  const float rn = rn_s;

  float4* vb = (float4*)(v + (size_t)b * N);
  const float4 vo = vb[t];
  const float4 vn = make_float4(q.x * rn, q.y * rn, q.z * rn, q.w * rn);
  vb[t] = vn;
  const float4 d = make_float4(vn.x - vo.x, vn.y - vo.y, vn.z - vo.z, vn.w - vo.w);
  float ds = d.x * d.x + d.y * d.y + d.z * d.z + d.w * d.w;
#pragma unroll
  for (int off = 32; off; off >>= 1) ds += __shfl_down(ds, off, 64);
  if ((t & 63) == 0) red[t >> 6] = ds;   // safe: t0's earlier read of red[] is
  __syncthreads();                       // separated by the sync after rn_s
  if (t == 0) {
    atomicAdd(diff, red[0] + red[1] + red[2] + red[3]);
    __threadfence();
    const int prev = atomicAdd(ctr, 1);
    if (prev == BATCH - 1) {            // last block: global decision
      const float tot = atomicAdd(diff, 0.0f);   // coherent read
      if (tot < TOL2) *done = 1;
      atomicExch(diff, 0.0f);
      atomicExch(ctr, 0);
    }
  }
}

// ---------------------------------------------------------------------------
extern "C" void kernel_launch(void* const* d_in, const int* in_sizes, int n_in,
                              void* d_out, int out_size, void* d_ws, size_t ws_size,
                              hipStream_t stream) {
  const float* M = (const float*)d_in[0];
  float* v = (float*)d_out;                       // v lives in d_out (32768 floats)
  float* y = (float*)d_ws;                        // unnormalized matvec result
  float* diff = (float*)((char*)d_ws + (size_t)NROWS * sizeof(float));
  int* ctr  = (int*)(diff + 1);
  int* done = (int*)(diff + 2);

  pi_init<<<(NROWS + 255) / 256, 256, 0, stream>>>(v, diff, ctr, done);
  for (int it = 0; it < 10; ++it) {
    pi_matvec<<<NROWS / 4, 256, 0, stream>>>(M, v, y, done);
    pi_finish<<<BATCH, 256, 0, stream>>>(v, y, diff, ctr, done);
  }
}